// Round 1
// baseline (1399.005 us; speedup 1.0000x reference)
//
#include <hip/hip_runtime.h>
#include <math.h>

// ws layout (float offsets). Total ~73.2 MB.
#define WT1_OFF 0
#define WT2_OFF 512
#define WT3_OFF 2560
#define WT4_OFF 4608
#define MV_OFF  6656
#define BUFA_OFF 16384
#define ZSZ (256*48*96*8)            // 9437184 floats
#define BUFB_OFF (BUFA_OFF + ZSZ)
#define PART_OFF (BUFA_OFF + 2*ZSZ)  // 1152*256 floats

// ---------------- K0: weight re-layout + mask precompute ----------------
// conv weights (co,ci,5,5) -> [ci][dy][dx][co] so inner co-loop reads 8
// contiguous floats (uniform address -> s_load_dwordx8).
__global__ void prep_kernel(const float* __restrict__ c1w, const float* __restrict__ c2w,
                            const float* __restrict__ c3w, const float* __restrict__ c4w,
                            const float* __restrict__ mask, float* __restrict__ ws) {
    int idx = blockIdx.x * blockDim.x + threadIdx.x;
    if (idx < 1600) {
        int co = idx & 7, rest = idx >> 3;
        int dx = rest % 5, dy = (rest / 5) % 5, ci = rest / 25;
        int src = ((co * 8 + ci) * 5 + dy) * 5 + dx;
        ws[WT2_OFF + idx] = c2w[src];
        ws[WT3_OFF + idx] = c3w[src];
        ws[WT4_OFF + idx] = c4w[src];
    }
    if (idx < 200) {
        int co = idx & 7, rest = idx >> 3;
        int dx = rest % 5, dy = rest / 5;
        ws[WT1_OFF + idx] = c1w[co * 25 + dy * 5 + dx];
    }
    if (idx < 1152) {
        int i = idx / 48, j = idx % 48;
        ws[MV_OFF + idx] = (mask[i * 8 * 384 + j * 8] > 0.5f) ? 1.0f : 0.0f;
    }
}

// ---------------- K1: downsample + conv1 + conv2 + relu + maxpool -------
// Each block: one 16x16 pooled z2 tile for one image.
__global__ __launch_bounds__(256) void k1_ds_conv12(
        const float* __restrict__ x, const float* __restrict__ wt1,
        const float* __restrict__ wt2, const float* __restrict__ c1b,
        const float* __restrict__ c2b, float* __restrict__ z2) {
    __shared__ __align__(16) float xdbuf[40][40];
    __shared__ __align__(16) float z1buf[36][37][8];  // padded stride vs bank conflicts
    const int tx = blockIdx.x, ty = blockIdx.y, b = blockIdx.z;
    const int tid = threadIdx.x;
    const int cy0 = ty * 32, cx0 = tx * 32;   // pre-pool tile origin in 96x192

    // phase 0: 2x2 average downsample into xdbuf (40x40 region, zero-padded)
    for (int i = tid; i < 1600; i += 256) {
        int iy = i / 40, ix = i % 40;
        int gy = cy0 - 4 + iy, gx = cx0 - 4 + ix;
        float v = 0.f;
        if (gy >= 0 && gy < 96 && gx >= 0 && gx < 192) {
            const float* p = x + (size_t)b * (192 * 384) + (2 * gy) * 384 + 2 * gx;
            float2 a = *(const float2*)p;
            float2 c = *(const float2*)(p + 384);
            v = (a.x + a.y + c.x + c.y) * 0.25f;
        }
        xdbuf[iy][ix] = v;
    }
    __syncthreads();

    // phase A: conv1 (1->8, +bias, no relu) into z1buf NHWC.
    // Pixels outside the image are set to 0 (conv2's SAME zero padding).
    for (int i = tid; i < 1296; i += 256) {
        int iy = i / 36, ix = i % 36;
        int gy = cy0 - 2 + iy, gx = cx0 - 2 + ix;
        float acc[8];
        if (gy >= 0 && gy < 96 && gx >= 0 && gx < 192) {
#pragma unroll
            for (int co = 0; co < 8; ++co) acc[co] = c1b[co];
#pragma unroll
            for (int dy = 0; dy < 5; ++dy)
#pragma unroll
                for (int dx = 0; dx < 5; ++dx) {
                    float v = xdbuf[iy + dy][ix + dx];
#pragma unroll
                    for (int co = 0; co < 8; ++co)
                        acc[co] = fmaf(v, wt1[(dy * 5 + dx) * 8 + co], acc[co]);
                }
        } else {
#pragma unroll
            for (int co = 0; co < 8; ++co) acc[co] = 0.f;
        }
        *(float4*)&z1buf[iy][ix][0] = make_float4(acc[0], acc[1], acc[2], acc[3]);
        *(float4*)&z1buf[iy][ix][4] = make_float4(acc[4], acc[5], acc[6], acc[7]);
    }
    __syncthreads();

    // phase B: conv2 (8->8) + relu + 2x2 maxpool. Thread owns a 2x2 patch.
    const int pr = tid >> 4, pc = tid & 15;
    float acc[4][8];
#pragma unroll
    for (int p = 0; p < 4; ++p)
#pragma unroll
        for (int co = 0; co < 8; ++co) acc[p][co] = c2b[co];

#pragma unroll
    for (int r = 0; r < 6; ++r) {          // z1 row window 2pr..2pr+5
        float v[6][8];
#pragma unroll
        for (int c = 0; c < 6; ++c) {
            float4 p0 = *(const float4*)&z1buf[2 * pr + r][2 * pc + c][0];
            float4 p1 = *(const float4*)&z1buf[2 * pr + r][2 * pc + c][4];
            v[c][0] = p0.x; v[c][1] = p0.y; v[c][2] = p0.z; v[c][3] = p0.w;
            v[c][4] = p1.x; v[c][5] = p1.y; v[c][6] = p1.z; v[c][7] = p1.w;
        }
#pragma unroll
        for (int ry = 0; ry < 2; ++ry) {
            int dy = r - ry;
            if (dy >= 0 && dy < 5) {
#pragma unroll
                for (int dx = 0; dx < 5; ++dx)
#pragma unroll
                    for (int ci = 0; ci < 8; ++ci) {
                        const float* wp = wt2 + ((ci * 5 + dy) * 5 + dx) * 8;
#pragma unroll
                        for (int rx = 0; rx < 2; ++rx) {
                            float vv = v[rx + dx][ci];
#pragma unroll
                            for (int co = 0; co < 8; ++co)
                                acc[ry * 2 + rx][co] = fmaf(vv, wp[co], acc[ry * 2 + rx][co]);
                        }
                    }
            }
        }
    }
    // relu + pool + store NHWC
    const int py = ty * 16 + pr, px = tx * 16 + pc;
    float o[8];
#pragma unroll
    for (int co = 0; co < 8; ++co) {
        float m = fmaxf(fmaxf(acc[0][co], acc[1][co]), fmaxf(acc[2][co], acc[3][co]));
        o[co] = fmaxf(m, 0.f);
    }
    float* dst = z2 + (((size_t)b * 48 + py) * 96 + px) * 8;
    *(float4*)dst = make_float4(o[0], o[1], o[2], o[3]);
    *(float4*)(dst + 4) = make_float4(o[4], o[5], o[6], o[7]);
}

// ---------------- K2/K3: generic 8->8 conv, NHWC, SAME, optional relu ---
__global__ __launch_bounds__(256) void conv8_kernel(
        const float* __restrict__ in, float* __restrict__ out,
        const float* __restrict__ wt, const float* __restrict__ bias, int do_relu) {
    __shared__ __align__(16) float inbuf[20][101][8];  // 64,640 B
    const int rt = blockIdx.x, b = blockIdx.y;
    const int ry0 = rt * 16;
    const int tid = threadIdx.x;

    // stage 20x100x8 region (zero-padded)
    for (int v4 = tid; v4 < 4000; v4 += 256) {
        int r = v4 / 200, rem = v4 % 200;
        int col = rem >> 1, half = rem & 1;
        int gy = ry0 - 2 + r, gc = col - 2;
        float4 val = make_float4(0.f, 0.f, 0.f, 0.f);
        if (gy >= 0 && gy < 48 && gc >= 0 && gc < 96)
            val = *(const float4*)(in + (((size_t)b * 48 + gy) * 96 + gc) * 8 + half * 4);
        *(float4*)&inbuf[r][col][half * 4] = val;
    }
    __syncthreads();

    const int rr = tid >> 4, cg = tid & 15;
    const int x0 = cg * 6;
    float acc[6][8];
#pragma unroll
    for (int p = 0; p < 6; ++p)
#pragma unroll
        for (int co = 0; co < 8; ++co) acc[p][co] = bias[co];

    for (int dy = 0; dy < 5; ++dy) {
        float v[10][8];
#pragma unroll
        for (int c = 0; c < 10; ++c) {
            float4 p0 = *(const float4*)&inbuf[rr + dy][x0 + c][0];
            float4 p1 = *(const float4*)&inbuf[rr + dy][x0 + c][4];
            v[c][0] = p0.x; v[c][1] = p0.y; v[c][2] = p0.z; v[c][3] = p0.w;
            v[c][4] = p1.x; v[c][5] = p1.y; v[c][6] = p1.z; v[c][7] = p1.w;
        }
#pragma unroll
        for (int dx = 0; dx < 5; ++dx)
#pragma unroll
            for (int ci = 0; ci < 8; ++ci) {
                const float* wp = wt + ((ci * 5 + dy) * 5 + dx) * 8;
#pragma unroll
                for (int p = 0; p < 6; ++p) {
                    float vv = v[p + dx][ci];
#pragma unroll
                    for (int co = 0; co < 8; ++co)
                        acc[p][co] = fmaf(vv, wp[co], acc[p][co]);
                }
            }
    }
#pragma unroll
    for (int p = 0; p < 6; ++p) {
        float o[8];
#pragma unroll
        for (int co = 0; co < 8; ++co)
            o[co] = do_relu ? fmaxf(acc[p][co], 0.f) : acc[p][co];
        float* dst = out + (((size_t)b * 48 + ry0 + rr) * 96 + (x0 + p)) * 8;
        *(float4*)dst = make_float4(o[0], o[1], o[2], o[3]);
        *(float4*)(dst + 4) = make_float4(o[4], o[5], o[6], o[7]);
    }
}

// ---------------- K4: per-feature MLP (pool fused into load) ------------
__global__ __launch_bounds__(256) void mlp_kernel(
        const float* __restrict__ z4, const float* __restrict__ W1,
        const float* __restrict__ b1, const float* __restrict__ W2,
        const float* __restrict__ b2, const float* __restrict__ W3,
        const float* __restrict__ mv, float* __restrict__ part) {
    const int f = blockIdx.x;
    const int bb = threadIdx.x;
    if (mv[f] == 0.f) { part[(size_t)f * 256 + bb] = 0.f; return; }
    const int y = f / 48, xcol = f % 48;
    const float* src = z4 + (((size_t)bb * 48 + 2 * y) * 96 + 2 * xcol) * 8;
    float p00[8], p01[8], p10[8], p11[8];
    {
        float4 a0 = *(const float4*)(src);
        float4 a1 = *(const float4*)(src + 4);
        float4 a2 = *(const float4*)(src + 8);
        float4 a3 = *(const float4*)(src + 12);
        float4 c0 = *(const float4*)(src + 96 * 8);
        float4 c1 = *(const float4*)(src + 96 * 8 + 4);
        float4 c2 = *(const float4*)(src + 96 * 8 + 8);
        float4 c3 = *(const float4*)(src + 96 * 8 + 12);
        p00[0]=a0.x;p00[1]=a0.y;p00[2]=a0.z;p00[3]=a0.w;p00[4]=a1.x;p00[5]=a1.y;p00[6]=a1.z;p00[7]=a1.w;
        p01[0]=a2.x;p01[1]=a2.y;p01[2]=a2.z;p01[3]=a2.w;p01[4]=a3.x;p01[5]=a3.y;p01[6]=a3.z;p01[7]=a3.w;
        p10[0]=c0.x;p10[1]=c0.y;p10[2]=c0.z;p10[3]=c0.w;p10[4]=c1.x;p10[5]=c1.y;p10[6]=c1.z;p10[7]=c1.w;
        p11[0]=c2.x;p11[1]=c2.y;p11[2]=c2.z;p11[3]=c2.w;p11[4]=c3.x;p11[5]=c3.y;p11[6]=c3.z;p11[7]=c3.w;
    }
    float h[8];
#pragma unroll
    for (int c = 0; c < 8; ++c)
        h[c] = fmaxf(fmaxf(p00[c], p01[c]), fmaxf(p10[c], p11[c]));

    const float* w1p = W1 + (size_t)f * 8 * 32;
    const float* b1p = b1 + (size_t)f * 32;
    float t1[32];
#pragma unroll
    for (int j = 0; j < 32; ++j) t1[j] = b1p[j];
    for (int c = 0; c < 8; ++c) {
        float hv = h[c];
        const float* wp = w1p + c * 32;
#pragma unroll
        for (int j = 0; j < 32; ++j) t1[j] = fmaf(hv, wp[j], t1[j]);
    }
#pragma unroll
    for (int j = 0; j < 32; ++j) t1[j] = fmaxf(t1[j], 0.f);

    const float* w2p = W2 + (size_t)f * 32 * 32;
    const float* b2p = b2 + (size_t)f * 32;
    float t2[32];
#pragma unroll
    for (int g = 0; g < 32; ++g) t2[g] = b2p[g];
    for (int j = 0; j < 32; ++j) {
        float tv = t1[j];
        const float* wp = w2p + j * 32;
#pragma unroll
        for (int g = 0; g < 32; ++g) t2[g] = fmaf(tv, wp[g], t2[g]);
    }
    const float* w3p = W3 + (size_t)f * 32;
    float s = 0.f;
#pragma unroll
    for (int g = 0; g < 32; ++g) s = fmaf(fmaxf(t2[g], 0.f), w3p[g], s);
    part[(size_t)f * 256 + bb] = s;
}

// ---------------- K5: reduce over features + bias + sigmoid -------------
__global__ void reduce_kernel(const float* __restrict__ part, const float* __restrict__ ab,
                              float* __restrict__ out) {
    int bb = threadIdx.x;
    float s0 = 0.f, s1 = 0.f, s2 = 0.f, s3 = 0.f;
    for (int f = 0; f < 1152; f += 4) {
        s0 += part[(size_t)(f + 0) * 256 + bb];
        s1 += part[(size_t)(f + 1) * 256 + bb];
        s2 += part[(size_t)(f + 2) * 256 + bb];
        s3 += part[(size_t)(f + 3) * 256 + bb];
    }
    float s = (s0 + s1) + (s2 + s3) + ab[0];
    out[bb] = 1.f / (1.f + expf(-s));
}

extern "C" void kernel_launch(void* const* d_in, const int* in_sizes, int n_in,
                              void* d_out, int out_size, void* d_ws, size_t ws_size,
                              hipStream_t stream) {
    const float* x    = (const float*)d_in[0];
    const float* mask = (const float*)d_in[1];
    const float* c1w  = (const float*)d_in[2];
    const float* c1b  = (const float*)d_in[3];
    const float* c2w  = (const float*)d_in[4];
    const float* c2b  = (const float*)d_in[5];
    const float* c3w  = (const float*)d_in[6];
    const float* c3b  = (const float*)d_in[7];
    const float* c4w  = (const float*)d_in[8];
    const float* c4b  = (const float*)d_in[9];
    const float* W1   = (const float*)d_in[10];
    const float* b1   = (const float*)d_in[11];
    const float* W2   = (const float*)d_in[12];
    const float* b2   = (const float*)d_in[13];
    const float* W3   = (const float*)d_in[14];
    const float* ab   = (const float*)d_in[15];
    float* ws = (float*)d_ws;

    float* wt1  = ws + WT1_OFF;
    float* wt2  = ws + WT2_OFF;
    float* wt3  = ws + WT3_OFF;
    float* wt4  = ws + WT4_OFF;
    float* mv   = ws + MV_OFF;
    float* bufA = ws + BUFA_OFF;   // z2, later z4pre
    float* bufB = ws + BUFB_OFF;   // z3
    float* part = ws + PART_OFF;

    prep_kernel<<<8, 256, 0, stream>>>(c1w, c2w, c3w, c4w, mask, ws);
    k1_ds_conv12<<<dim3(6, 3, 256), 256, 0, stream>>>(x, wt1, wt2, c1b, c2b, bufA);
    conv8_kernel<<<dim3(3, 256), 256, 0, stream>>>(bufA, bufB, wt3, c3b, 0); // conv3
    conv8_kernel<<<dim3(3, 256), 256, 0, stream>>>(bufB, bufA, wt4, c4b, 1); // conv4+relu
    mlp_kernel<<<1152, 256, 0, stream>>>(bufA, W1, b1, W2, b2, W3, mv, part);
    reduce_kernel<<<1, 256, 0, stream>>>(part, ab, (float*)d_out);
}

// Round 2
// 425.472 us; speedup vs baseline: 3.2881x; 3.2881x over previous
//
#include <hip/hip_runtime.h>
#include <math.h>

// ws layout (float offsets). Total ~77 MB.
#define WT1_OFF 0
#define WT2_OFF 512
#define WT3_OFF 2560
#define WT4_OFF 4608
#define MV_OFF  6656
#define BUFA_OFF 16384
#define ZSZ (256*48*96*8)            // 9437184 floats
#define BUFB_OFF (BUFA_OFF + ZSZ)
#define PART_OFF (BUFA_OFF + 2*ZSZ)  // 1152*256 floats

// ---------------- K0: weight re-layout + mask precompute ----------------
__global__ void prep_kernel(const float* __restrict__ c1w, const float* __restrict__ c2w,
                            const float* __restrict__ c3w, const float* __restrict__ c4w,
                            const float* __restrict__ mask, float* __restrict__ ws) {
    int idx = blockIdx.x * blockDim.x + threadIdx.x;
    if (idx < 1600) {
        int co = idx & 7, rest = idx >> 3;
        int dx = rest % 5, dy = (rest / 5) % 5, ci = rest / 25;
        int src = ((co * 8 + ci) * 5 + dy) * 5 + dx;
        ws[WT2_OFF + idx] = c2w[src];
        ws[WT3_OFF + idx] = c3w[src];
        ws[WT4_OFF + idx] = c4w[src];
    }
    if (idx < 200) {
        int co = idx & 7, rest = idx >> 3;
        int dx = rest % 5, dy = rest / 5;
        ws[WT1_OFF + idx] = c1w[co * 25 + dy * 5 + dx];
    }
    if (idx < 1152) {
        int i = idx / 48, j = idx % 48;
        ws[MV_OFF + idx] = (mask[i * 8 * 384 + j * 8] > 0.5f) ? 1.0f : 0.0f;
    }
}

// ---------------- K1: ds + conv1 + conv2 + relu + maxpool (conv8-style) --
// Block tile: 16 conv2-rows x 64 conv2-cols on the 96x192 grid -> pooled 8x32.
// Thread (rr = tid>>4, cg = tid&15): row rr, cols x0=4*cg .. x0+3.
__global__ __launch_bounds__(256) void k1_fused(
        const float* __restrict__ x, const float* __restrict__ wt1,
        const float* __restrict__ wt2, const float* __restrict__ c1b,
        const float* __restrict__ c2b, float* __restrict__ z2) {
    __shared__ float xdbuf[24][72];                    // 6,912 B
    __shared__ __align__(16) float z1buf[20][68][8];   // 43,520 B
    const int rt = blockIdx.x;   // 0..5  (row tile)
    const int ct = blockIdx.y;   // 0..2  (col tile)
    const int b  = blockIdx.z;
    const int tid = threadIdx.x;
    const int ry0 = rt * 16, cx0 = ct * 64;

    // phase 0: 2x2 avg downsample into xdbuf (rows ry0-4.., cols cx0-4..),
    // two xd pixels per float4 pair of loads.
    for (int i = tid; i < 24 * 36; i += 256) {
        int pr = i / 36, pj = i % 36;
        int gy = ry0 - 4 + pr, gx = cx0 - 4 + 2 * pj;
        float v0 = 0.f, v1 = 0.f;
        if (gy >= 0 && gy < 96 && gx >= 0 && gx < 192) {
            const float* p = x + (size_t)b * (192 * 384) + (2 * gy) * 384 + 2 * gx;
            float4 a = *(const float4*)p;
            float4 c = *(const float4*)(p + 384);
            v0 = (a.x + a.y + c.x + c.y) * 0.25f;
            v1 = (a.z + a.w + c.z + c.w) * 0.25f;
        }
        xdbuf[pr][2 * pj]     = v0;
        xdbuf[pr][2 * pj + 1] = v1;
    }
    __syncthreads();

    // phase 1: conv1 (1->8, +bias) into z1buf NHWC; out-of-image -> 0.
    for (int i = tid; i < 20 * 68; i += 256) {
        int iy = i / 68, ix = i % 68;
        int gy = ry0 - 2 + iy, gx = cx0 - 2 + ix;
        float acc[8];
        if (gy >= 0 && gy < 96 && gx >= 0 && gx < 192) {
#pragma unroll
            for (int co = 0; co < 8; ++co) acc[co] = c1b[co];
#pragma unroll
            for (int dy = 0; dy < 5; ++dy)
#pragma unroll
                for (int dx = 0; dx < 5; ++dx) {
                    float v = xdbuf[iy + dy][ix + dx];
#pragma unroll
                    for (int co = 0; co < 8; ++co)
                        acc[co] = fmaf(v, wt1[(dy * 5 + dx) * 8 + co], acc[co]);
                }
        } else {
#pragma unroll
            for (int co = 0; co < 8; ++co) acc[co] = 0.f;
        }
        *(float4*)&z1buf[iy][ix][0] = make_float4(acc[0], acc[1], acc[2], acc[3]);
        *(float4*)&z1buf[iy][ix][4] = make_float4(acc[4], acc[5], acc[6], acc[7]);
    }
    __syncthreads();

    // phase 2: conv2 (8->8) over 4 consecutive cols, row-major sweeps.
    const int rr = tid >> 4, cg = tid & 15;
    const int x0 = cg * 4;
    float acc[4][8];
#pragma unroll
    for (int p = 0; p < 4; ++p)
#pragma unroll
        for (int co = 0; co < 8; ++co) acc[p][co] = c2b[co];

    for (int dy = 0; dy < 5; ++dy) {
        float v[8][8];
#pragma unroll
        for (int c = 0; c < 8; ++c) {
            float4 p0 = *(const float4*)&z1buf[rr + dy][x0 + c][0];
            float4 p1 = *(const float4*)&z1buf[rr + dy][x0 + c][4];
            v[c][0] = p0.x; v[c][1] = p0.y; v[c][2] = p0.z; v[c][3] = p0.w;
            v[c][4] = p1.x; v[c][5] = p1.y; v[c][6] = p1.z; v[c][7] = p1.w;
        }
#pragma unroll
        for (int dx = 0; dx < 5; ++dx)
#pragma unroll
            for (int ci = 0; ci < 8; ++ci) {
                const float* wp = wt2 + ((ci * 5 + dy) * 5 + dx) * 8;
#pragma unroll
                for (int p = 0; p < 4; ++p) {
                    float vv = v[p + dx][ci];
#pragma unroll
                    for (int co = 0; co < 8; ++co)
                        acc[p][co] = fmaf(vv, wp[co], acc[p][co]);
                }
            }
    }

    // relu + 2x2 maxpool: col-pairs in-thread, row pair via shfl_xor(16).
    float po[2][8];
#pragma unroll
    for (int q = 0; q < 2; ++q)
#pragma unroll
        for (int co = 0; co < 8; ++co)
            po[q][co] = fmaxf(fmaxf(acc[2 * q][co], acc[2 * q + 1][co]), 0.f);
#pragma unroll
    for (int q = 0; q < 2; ++q)
#pragma unroll
        for (int co = 0; co < 8; ++co) {
            float other = __shfl_xor(po[q][co], 16);
            po[q][co] = fmaxf(po[q][co], other);
        }
    if ((rr & 1) == 0) {
        int pyr = (ry0 + rr) >> 1;
        int pxc = (cx0 + x0) >> 1;
        float* dst = z2 + (((size_t)b * 48 + pyr) * 96 + pxc) * 8;
        *(float4*)(dst + 0)  = make_float4(po[0][0], po[0][1], po[0][2], po[0][3]);
        *(float4*)(dst + 4)  = make_float4(po[0][4], po[0][5], po[0][6], po[0][7]);
        *(float4*)(dst + 8)  = make_float4(po[1][0], po[1][1], po[1][2], po[1][3]);
        *(float4*)(dst + 12) = make_float4(po[1][4], po[1][5], po[1][6], po[1][7]);
    }
}

// ---------------- K2/K3: generic 8->8 conv, NHWC, SAME, optional relu ---
__global__ __launch_bounds__(256) void conv8_kernel(
        const float* __restrict__ in, float* __restrict__ out,
        const float* __restrict__ wt, const float* __restrict__ bias, int do_relu) {
    __shared__ __align__(16) float inbuf[20][101][8];  // 64,640 B
    const int rt = blockIdx.x, b = blockIdx.y;
    const int ry0 = rt * 16;
    const int tid = threadIdx.x;

    for (int v4 = tid; v4 < 4000; v4 += 256) {
        int r = v4 / 200, rem = v4 % 200;
        int col = rem >> 1, half = rem & 1;
        int gy = ry0 - 2 + r, gc = col - 2;
        float4 val = make_float4(0.f, 0.f, 0.f, 0.f);
        if (gy >= 0 && gy < 48 && gc >= 0 && gc < 96)
            val = *(const float4*)(in + (((size_t)b * 48 + gy) * 96 + gc) * 8 + half * 4);
        *(float4*)&inbuf[r][col][half * 4] = val;
    }
    __syncthreads();

    const int rr = tid >> 4, cg = tid & 15;
    const int x0 = cg * 6;
    float acc[6][8];
#pragma unroll
    for (int p = 0; p < 6; ++p)
#pragma unroll
        for (int co = 0; co < 8; ++co) acc[p][co] = bias[co];

    for (int dy = 0; dy < 5; ++dy) {
        float v[10][8];
#pragma unroll
        for (int c = 0; c < 10; ++c) {
            float4 p0 = *(const float4*)&inbuf[rr + dy][x0 + c][0];
            float4 p1 = *(const float4*)&inbuf[rr + dy][x0 + c][4];
            v[c][0] = p0.x; v[c][1] = p0.y; v[c][2] = p0.z; v[c][3] = p0.w;
            v[c][4] = p1.x; v[c][5] = p1.y; v[c][6] = p1.z; v[c][7] = p1.w;
        }
#pragma unroll
        for (int dx = 0; dx < 5; ++dx)
#pragma unroll
            for (int ci = 0; ci < 8; ++ci) {
                const float* wp = wt + ((ci * 5 + dy) * 5 + dx) * 8;
#pragma unroll
                for (int p = 0; p < 6; ++p) {
                    float vv = v[p + dx][ci];
#pragma unroll
                    for (int co = 0; co < 8; ++co)
                        acc[p][co] = fmaf(vv, wp[co], acc[p][co]);
                }
            }
    }
#pragma unroll
    for (int p = 0; p < 6; ++p) {
        float o[8];
#pragma unroll
        for (int co = 0; co < 8; ++co)
            o[co] = do_relu ? fmaxf(acc[p][co], 0.f) : acc[p][co];
        float* dst = out + (((size_t)b * 48 + ry0 + rr) * 96 + (x0 + p)) * 8;
        *(float4*)dst = make_float4(o[0], o[1], o[2], o[3]);
        *(float4*)(dst + 4) = make_float4(o[4], o[5], o[6], o[7]);
    }
}

// ---------------- K4: per-feature MLP (pool fused into load) ------------
__global__ __launch_bounds__(256) void mlp_kernel(
        const float* __restrict__ z4, const float* __restrict__ W1,
        const float* __restrict__ b1, const float* __restrict__ W2,
        const float* __restrict__ b2, const float* __restrict__ W3,
        const float* __restrict__ mv, float* __restrict__ part) {
    const int f = blockIdx.x;
    const int bb = threadIdx.x;
    if (mv[f] == 0.f) { part[(size_t)f * 256 + bb] = 0.f; return; }
    const int y = f / 48, xcol = f % 48;
    const float* src = z4 + (((size_t)bb * 48 + 2 * y) * 96 + 2 * xcol) * 8;
    float p00[8], p01[8], p10[8], p11[8];
    {
        float4 a0 = *(const float4*)(src);
        float4 a1 = *(const float4*)(src + 4);
        float4 a2 = *(const float4*)(src + 8);
        float4 a3 = *(const float4*)(src + 12);
        float4 c0 = *(const float4*)(src + 96 * 8);
        float4 c1 = *(const float4*)(src + 96 * 8 + 4);
        float4 c2 = *(const float4*)(src + 96 * 8 + 8);
        float4 c3 = *(const float4*)(src + 96 * 8 + 12);
        p00[0]=a0.x;p00[1]=a0.y;p00[2]=a0.z;p00[3]=a0.w;p00[4]=a1.x;p00[5]=a1.y;p00[6]=a1.z;p00[7]=a1.w;
        p01[0]=a2.x;p01[1]=a2.y;p01[2]=a2.z;p01[3]=a2.w;p01[4]=a3.x;p01[5]=a3.y;p01[6]=a3.z;p01[7]=a3.w;
        p10[0]=c0.x;p10[1]=c0.y;p10[2]=c0.z;p10[3]=c0.w;p10[4]=c1.x;p10[5]=c1.y;p10[6]=c1.z;p10[7]=c1.w;
        p11[0]=c2.x;p11[1]=c2.y;p11[2]=c2.z;p11[3]=c2.w;p11[4]=c3.x;p11[5]=c3.y;p11[6]=c3.z;p11[7]=c3.w;
    }
    float h[8];
#pragma unroll
    for (int c = 0; c < 8; ++c)
        h[c] = fmaxf(fmaxf(p00[c], p01[c]), fmaxf(p10[c], p11[c]));

    const float* w1p = W1 + (size_t)f * 8 * 32;
    const float* b1p = b1 + (size_t)f * 32;
    float t1[32];
#pragma unroll
    for (int j = 0; j < 32; ++j) t1[j] = b1p[j];
    for (int c = 0; c < 8; ++c) {
        float hv = h[c];
        const float* wp = w1p + c * 32;
#pragma unroll
        for (int j = 0; j < 32; ++j) t1[j] = fmaf(hv, wp[j], t1[j]);
    }
#pragma unroll
    for (int j = 0; j < 32; ++j) t1[j] = fmaxf(t1[j], 0.f);

    const float* w2p = W2 + (size_t)f * 32 * 32;
    const float* b2p = b2 + (size_t)f * 32;
    float t2[32];
#pragma unroll
    for (int g = 0; g < 32; ++g) t2[g] = b2p[g];
    for (int j = 0; j < 32; ++j) {
        float tv = t1[j];
        const float* wp = w2p + j * 32;
#pragma unroll
        for (int g = 0; g < 32; ++g) t2[g] = fmaf(tv, wp[g], t2[g]);
    }
    const float* w3p = W3 + (size_t)f * 32;
    float s = 0.f;
#pragma unroll
    for (int g = 0; g < 32; ++g) s = fmaf(fmaxf(t2[g], 0.f), w3p[g], s);
    part[(size_t)f * 256 + bb] = s;
}

// ---------------- K5: reduce over features + bias + sigmoid -------------
__global__ void reduce_kernel(const float* __restrict__ part, const float* __restrict__ ab,
                              float* __restrict__ out) {
    int bb = threadIdx.x;
    float s0 = 0.f, s1 = 0.f, s2 = 0.f, s3 = 0.f;
    for (int f = 0; f < 1152; f += 4) {
        s0 += part[(size_t)(f + 0) * 256 + bb];
        s1 += part[(size_t)(f + 1) * 256 + bb];
        s2 += part[(size_t)(f + 2) * 256 + bb];
        s3 += part[(size_t)(f + 3) * 256 + bb];
    }
    float s = (s0 + s1) + (s2 + s3) + ab[0];
    out[bb] = 1.f / (1.f + expf(-s));
}

extern "C" void kernel_launch(void* const* d_in, const int* in_sizes, int n_in,
                              void* d_out, int out_size, void* d_ws, size_t ws_size,
                              hipStream_t stream) {
    const float* x    = (const float*)d_in[0];
    const float* mask = (const float*)d_in[1];
    const float* c1w  = (const float*)d_in[2];
    const float* c1b  = (const float*)d_in[3];
    const float* c2w  = (const float*)d_in[4];
    const float* c2b  = (const float*)d_in[5];
    const float* c3w  = (const float*)d_in[6];
    const float* c3b  = (const float*)d_in[7];
    const float* c4w  = (const float*)d_in[8];
    const float* c4b  = (const float*)d_in[9];
    const float* W1   = (const float*)d_in[10];
    const float* b1   = (const float*)d_in[11];
    const float* W2   = (const float*)d_in[12];
    const float* b2   = (const float*)d_in[13];
    const float* W3   = (const float*)d_in[14];
    const float* ab   = (const float*)d_in[15];
    float* ws = (float*)d_ws;

    float* wt1  = ws + WT1_OFF;
    float* wt2  = ws + WT2_OFF;
    float* wt3  = ws + WT3_OFF;
    float* wt4  = ws + WT4_OFF;
    float* mv   = ws + MV_OFF;
    float* bufA = ws + BUFA_OFF;   // z2, later z4
    float* bufB = ws + BUFB_OFF;   // z3
    float* part = ws + PART_OFF;

    prep_kernel<<<8, 256, 0, stream>>>(c1w, c2w, c3w, c4w, mask, ws);
    k1_fused<<<dim3(6, 3, 256), 256, 0, stream>>>(x, wt1, wt2, c1b, c2b, bufA);
    conv8_kernel<<<dim3(3, 256), 256, 0, stream>>>(bufA, bufB, wt3, c3b, 0); // conv3
    conv8_kernel<<<dim3(3, 256), 256, 0, stream>>>(bufB, bufA, wt4, c4b, 1); // conv4+relu
    mlp_kernel<<<1152, 256, 0, stream>>>(bufA, W1, b1, W2, b2, W3, mv, part);
    reduce_kernel<<<1, 256, 0, stream>>>(part, ab, (float*)d_out);
}

// Round 3
// 380.806 us; speedup vs baseline: 3.6738x; 1.1173x over previous
//
#include <hip/hip_runtime.h>
#include <math.h>

// ws layout (float offsets). Total ~77 MB.
#define WT1_OFF 0
#define WT2_OFF 512
#define WT3_OFF 2560
#define WT4_OFF 4608
#define MV_OFF  6656
#define BUFA_OFF 16384
#define ZSZ (256*48*96*8)            // 9437184 floats
#define BUFB_OFF (BUFA_OFF + ZSZ)
#define PART_OFF (BUFA_OFF + 2*ZSZ)  // 1152*256 floats

// Bijective LDS swizzle: float index for (pixel, channel-half). XORs bank
// bits [4:2] with pixel bits [5:3]; float4 groups stay contiguous/aligned.
// Write and read MUST both use this map (rule #21).
__device__ __forceinline__ int swz8(int pix) {
    return (pix * 8) ^ (((pix >> 3) & 7) << 2);
}

// ---------------- K0: weight re-layout + mask precompute ----------------
__global__ void prep_kernel(const float* __restrict__ c1w, const float* __restrict__ c2w,
                            const float* __restrict__ c3w, const float* __restrict__ c4w,
                            const float* __restrict__ mask, float* __restrict__ ws) {
    int idx = blockIdx.x * blockDim.x + threadIdx.x;
    if (idx < 1600) {
        int co = idx & 7, rest = idx >> 3;
        int dx = rest % 5, dy = (rest / 5) % 5, ci = rest / 25;
        int src = ((co * 8 + ci) * 5 + dy) * 5 + dx;
        ws[WT2_OFF + idx] = c2w[src];
        ws[WT3_OFF + idx] = c3w[src];
        ws[WT4_OFF + idx] = c4w[src];
    }
    if (idx < 200) {
        int co = idx & 7, rest = idx >> 3;
        int dx = rest % 5, dy = rest / 5;
        ws[WT1_OFF + idx] = c1w[co * 25 + dy * 5 + dx];
    }
    if (idx < 1152) {
        int i = idx / 48, j = idx % 48;
        ws[MV_OFF + idx] = (mask[i * 8 * 384 + j * 8] > 0.5f) ? 1.0f : 0.0f;
    }
}

// ---------------- K1: ds + conv1 + conv2 + relu + maxpool ----------------
// Block tile: 16 conv2-rows x 64 conv2-cols -> pooled 8x32.
__global__ __launch_bounds__(256) void k1_fused(
        const float* __restrict__ x, const float* __restrict__ wt1,
        const float* __restrict__ wt2, const float* __restrict__ c1b,
        const float* __restrict__ c2b, float* __restrict__ z2) {
    __shared__ float xdbuf[24][72];                 // 6,912 B
    __shared__ __align__(16) float z1f[20 * 68 * 8]; // 43,520 B, swizzled NHWC
    const int rt = blockIdx.x;   // 0..5
    const int ct = blockIdx.y;   // 0..2
    const int b  = blockIdx.z;
    const int tid = threadIdx.x;
    const int ry0 = rt * 16, cx0 = ct * 64;

    // phase 0: 2x2 avg downsample into xdbuf
    for (int i = tid; i < 24 * 36; i += 256) {
        int pr = i / 36, pj = i % 36;
        int gy = ry0 - 4 + pr, gx = cx0 - 4 + 2 * pj;
        float v0 = 0.f, v1 = 0.f;
        if (gy >= 0 && gy < 96 && gx >= 0 && gx < 192) {
            const float* p = x + (size_t)b * (192 * 384) + (2 * gy) * 384 + 2 * gx;
            float4 a = *(const float4*)p;
            float4 c = *(const float4*)(p + 384);
            v0 = (a.x + a.y + c.x + c.y) * 0.25f;
            v1 = (a.z + a.w + c.z + c.w) * 0.25f;
        }
        xdbuf[pr][2 * pj]     = v0;
        xdbuf[pr][2 * pj + 1] = v1;
    }
    __syncthreads();

    // phase 1: conv1 (1->8, +bias) into swizzled z1f; out-of-image -> 0.
    for (int i = tid; i < 20 * 68; i += 256) {
        int iy = i / 68, ix = i % 68;
        int gy = ry0 - 2 + iy, gx = cx0 - 2 + ix;
        float acc[8];
        if (gy >= 0 && gy < 96 && gx >= 0 && gx < 192) {
#pragma unroll
            for (int co = 0; co < 8; ++co) acc[co] = c1b[co];
#pragma unroll
            for (int dy = 0; dy < 5; ++dy)
#pragma unroll
                for (int dx = 0; dx < 5; ++dx) {
                    float v = xdbuf[iy + dy][ix + dx];
#pragma unroll
                    for (int co = 0; co < 8; ++co)
                        acc[co] = fmaf(v, wt1[(dy * 5 + dx) * 8 + co], acc[co]);
                }
        } else {
#pragma unroll
            for (int co = 0; co < 8; ++co) acc[co] = 0.f;
        }
        int s = swz8(i);
        *(float4*)&z1f[s]     = make_float4(acc[0], acc[1], acc[2], acc[3]);
        *(float4*)&z1f[s ^ 4] = make_float4(acc[4], acc[5], acc[6], acc[7]);
    }
    __syncthreads();

    // phase 2: conv2 (8->8) over 4 consecutive cols per thread.
    const int rr = tid >> 4, cg = tid & 15;
    const int x0 = cg * 4;
    float acc[4][8];
#pragma unroll
    for (int p = 0; p < 4; ++p)
#pragma unroll
        for (int co = 0; co < 8; ++co) acc[p][co] = c2b[co];

#pragma unroll
    for (int dy = 0; dy < 5; ++dy) {
        const int rowbase = (rr + dy) * 68 + x0;
        float v[8][8];
#pragma unroll
        for (int c = 0; c < 8; ++c) {
            int s = swz8(rowbase + c);
            float4 p0 = *(const float4*)&z1f[s];
            float4 p1 = *(const float4*)&z1f[s ^ 4];
            v[c][0] = p0.x; v[c][1] = p0.y; v[c][2] = p0.z; v[c][3] = p0.w;
            v[c][4] = p1.x; v[c][5] = p1.y; v[c][6] = p1.z; v[c][7] = p1.w;
        }
#pragma unroll
        for (int dx = 0; dx < 5; ++dx)
#pragma unroll
            for (int ci = 0; ci < 8; ++ci) {
                const float* wp = wt2 + ((ci * 5 + dy) * 5 + dx) * 8;
#pragma unroll
                for (int p = 0; p < 4; ++p) {
                    float vv = v[p + dx][ci];
#pragma unroll
                    for (int co = 0; co < 8; ++co)
                        acc[p][co] = fmaf(vv, wp[co], acc[p][co]);
                }
            }
    }

    // relu + 2x2 maxpool: col-pairs in-thread, row pair via shfl_xor(16).
    float po[2][8];
#pragma unroll
    for (int q = 0; q < 2; ++q)
#pragma unroll
        for (int co = 0; co < 8; ++co)
            po[q][co] = fmaxf(fmaxf(acc[2 * q][co], acc[2 * q + 1][co]), 0.f);
#pragma unroll
    for (int q = 0; q < 2; ++q)
#pragma unroll
        for (int co = 0; co < 8; ++co) {
            float other = __shfl_xor(po[q][co], 16);
            po[q][co] = fmaxf(po[q][co], other);
        }
    if ((rr & 1) == 0) {
        int pyr = (ry0 + rr) >> 1;
        int pxc = (cx0 + x0) >> 1;
        float* dst = z2 + (((size_t)b * 48 + pyr) * 96 + pxc) * 8;
        *(float4*)(dst + 0)  = make_float4(po[0][0], po[0][1], po[0][2], po[0][3]);
        *(float4*)(dst + 4)  = make_float4(po[0][4], po[0][5], po[0][6], po[0][7]);
        *(float4*)(dst + 8)  = make_float4(po[1][0], po[1][1], po[1][2], po[1][3]);
        *(float4*)(dst + 12) = make_float4(po[1][4], po[1][5], po[1][6], po[1][7]);
    }
}

// ---------------- K2/K3: 8->8 conv, NHWC, SAME, optional relu -----------
// Tile: 16 rows x 48 cols (2 col tiles). LDS 33.3 KB -> 4 blocks/CU.
__global__ __launch_bounds__(256) void conv8_kernel(
        const float* __restrict__ in, float* __restrict__ out,
        const float* __restrict__ wt, const float* __restrict__ bias, int do_relu) {
    __shared__ __align__(16) float inbuf[20 * 52 * 8];  // 33,280 B, swizzled
    const int rt = blockIdx.x, ctile = blockIdx.y, b = blockIdx.z;
    const int ry0 = rt * 16, cx0 = ctile * 48;
    const int tid = threadIdx.x;

    // stage 20x52x8 region (zero-padded), swizzled writes
    for (int u = tid; u < 20 * 52 * 2; u += 256) {
        int half = u & 1, pix = u >> 1;
        int r = pix / 52, col = pix % 52;
        int gy = ry0 - 2 + r, gc = cx0 - 2 + col;
        float4 val = make_float4(0.f, 0.f, 0.f, 0.f);
        if (gy >= 0 && gy < 48 && gc >= 0 && gc < 96)
            val = *(const float4*)(in + (((size_t)b * 48 + gy) * 96 + gc) * 8 + half * 4);
        *(float4*)&inbuf[swz8(pix) ^ (half * 4)] = val;
    }
    __syncthreads();

    const int rr = tid >> 4, cg = tid & 15;
    const int x0 = cg * 3;
    float acc[3][8];
#pragma unroll
    for (int p = 0; p < 3; ++p)
#pragma unroll
        for (int co = 0; co < 8; ++co) acc[p][co] = bias[co];

#pragma unroll
    for (int dy = 0; dy < 5; ++dy) {
        const int rowbase = (rr + dy) * 52 + x0;
        float v[7][8];
#pragma unroll
        for (int c = 0; c < 7; ++c) {
            int s = swz8(rowbase + c);
            float4 p0 = *(const float4*)&inbuf[s];
            float4 p1 = *(const float4*)&inbuf[s ^ 4];
            v[c][0] = p0.x; v[c][1] = p0.y; v[c][2] = p0.z; v[c][3] = p0.w;
            v[c][4] = p1.x; v[c][5] = p1.y; v[c][6] = p1.z; v[c][7] = p1.w;
        }
#pragma unroll
        for (int dx = 0; dx < 5; ++dx)
#pragma unroll
            for (int ci = 0; ci < 8; ++ci) {
                const float* wp = wt + ((ci * 5 + dy) * 5 + dx) * 8;
#pragma unroll
                for (int p = 0; p < 3; ++p) {
                    float vv = v[p + dx][ci];
#pragma unroll
                    for (int co = 0; co < 8; ++co)
                        acc[p][co] = fmaf(vv, wp[co], acc[p][co]);
                }
            }
    }
#pragma unroll
    for (int p = 0; p < 3; ++p) {
        float o[8];
#pragma unroll
        for (int co = 0; co < 8; ++co)
            o[co] = do_relu ? fmaxf(acc[p][co], 0.f) : acc[p][co];
        float* dst = out + (((size_t)b * 48 + ry0 + rr) * 96 + (cx0 + x0 + p)) * 8;
        *(float4*)dst = make_float4(o[0], o[1], o[2], o[3]);
        *(float4*)(dst + 4) = make_float4(o[4], o[5], o[6], o[7]);
    }
}

// ---------------- K4: per-feature MLP (pool fused into load) ------------
__global__ __launch_bounds__(256) void mlp_kernel(
        const float* __restrict__ z4, const float* __restrict__ W1,
        const float* __restrict__ b1, const float* __restrict__ W2,
        const float* __restrict__ b2, const float* __restrict__ W3,
        const float* __restrict__ mv, float* __restrict__ part) {
    const int f = blockIdx.x;
    const int bb = threadIdx.x;
    if (mv[f] == 0.f) { part[(size_t)f * 256 + bb] = 0.f; return; }
    const int y = f / 48, xcol = f % 48;
    const float* src = z4 + (((size_t)bb * 48 + 2 * y) * 96 + 2 * xcol) * 8;
    float p00[8], p01[8], p10[8], p11[8];
    {
        float4 a0 = *(const float4*)(src);
        float4 a1 = *(const float4*)(src + 4);
        float4 a2 = *(const float4*)(src + 8);
        float4 a3 = *(const float4*)(src + 12);
        float4 c0 = *(const float4*)(src + 96 * 8);
        float4 c1 = *(const float4*)(src + 96 * 8 + 4);
        float4 c2 = *(const float4*)(src + 96 * 8 + 8);
        float4 c3 = *(const float4*)(src + 96 * 8 + 12);
        p00[0]=a0.x;p00[1]=a0.y;p00[2]=a0.z;p00[3]=a0.w;p00[4]=a1.x;p00[5]=a1.y;p00[6]=a1.z;p00[7]=a1.w;
        p01[0]=a2.x;p01[1]=a2.y;p01[2]=a2.z;p01[3]=a2.w;p01[4]=a3.x;p01[5]=a3.y;p01[6]=a3.z;p01[7]=a3.w;
        p10[0]=c0.x;p10[1]=c0.y;p10[2]=c0.z;p10[3]=c0.w;p10[4]=c1.x;p10[5]=c1.y;p10[6]=c1.z;p10[7]=c1.w;
        p11[0]=c2.x;p11[1]=c2.y;p11[2]=c2.z;p11[3]=c2.w;p11[4]=c3.x;p11[5]=c3.y;p11[6]=c3.z;p11[7]=c3.w;
    }
    float h[8];
#pragma unroll
    for (int c = 0; c < 8; ++c)
        h[c] = fmaxf(fmaxf(p00[c], p01[c]), fmaxf(p10[c], p11[c]));

    const float* w1p = W1 + (size_t)f * 8 * 32;
    const float* b1p = b1 + (size_t)f * 32;
    float t1[32];
#pragma unroll
    for (int j = 0; j < 32; ++j) t1[j] = b1p[j];
    for (int c = 0; c < 8; ++c) {
        float hv = h[c];
        const float* wp = w1p + c * 32;
#pragma unroll
        for (int j = 0; j < 32; ++j) t1[j] = fmaf(hv, wp[j], t1[j]);
    }
#pragma unroll
    for (int j = 0; j < 32; ++j) t1[j] = fmaxf(t1[j], 0.f);

    const float* w2p = W2 + (size_t)f * 32 * 32;
    const float* b2p = b2 + (size_t)f * 32;
    float t2[32];
#pragma unroll
    for (int g = 0; g < 32; ++g) t2[g] = b2p[g];
    for (int j = 0; j < 32; ++j) {
        float tv = t1[j];
        const float* wp = w2p + j * 32;
#pragma unroll
        for (int g = 0; g < 32; ++g) t2[g] = fmaf(tv, wp[g], t2[g]);
    }
    const float* w3p = W3 + (size_t)f * 32;
    float s = 0.f;
#pragma unroll
    for (int g = 0; g < 32; ++g) s = fmaf(fmaxf(t2[g], 0.f), w3p[g], s);
    part[(size_t)f * 256 + bb] = s;
}

// ---------------- K5: reduce over features + bias + sigmoid -------------
__global__ void reduce_kernel(const float* __restrict__ part, const float* __restrict__ ab,
                              float* __restrict__ out) {
    int bb = threadIdx.x;
    float s0 = 0.f, s1 = 0.f, s2 = 0.f, s3 = 0.f;
    for (int f = 0; f < 1152; f += 4) {
        s0 += part[(size_t)(f + 0) * 256 + bb];
        s1 += part[(size_t)(f + 1) * 256 + bb];
        s2 += part[(size_t)(f + 2) * 256 + bb];
        s3 += part[(size_t)(f + 3) * 256 + bb];
    }
    float s = (s0 + s1) + (s2 + s3) + ab[0];
    out[bb] = 1.f / (1.f + expf(-s));
}

extern "C" void kernel_launch(void* const* d_in, const int* in_sizes, int n_in,
                              void* d_out, int out_size, void* d_ws, size_t ws_size,
                              hipStream_t stream) {
    const float* x    = (const float*)d_in[0];
    const float* mask = (const float*)d_in[1];
    const float* c1w  = (const float*)d_in[2];
    const float* c1b  = (const float*)d_in[3];
    const float* c2w  = (const float*)d_in[4];
    const float* c2b  = (const float*)d_in[5];
    const float* c3w  = (const float*)d_in[6];
    const float* c3b  = (const float*)d_in[7];
    const float* c4w  = (const float*)d_in[8];
    const float* c4b  = (const float*)d_in[9];
    const float* W1   = (const float*)d_in[10];
    const float* b1   = (const float*)d_in[11];
    const float* W2   = (const float*)d_in[12];
    const float* b2   = (const float*)d_in[13];
    const float* W3   = (const float*)d_in[14];
    const float* ab   = (const float*)d_in[15];
    float* ws = (float*)d_ws;

    float* wt1  = ws + WT1_OFF;
    float* wt2  = ws + WT2_OFF;
    float* wt3  = ws + WT3_OFF;
    float* wt4  = ws + WT4_OFF;
    float* mv   = ws + MV_OFF;
    float* bufA = ws + BUFA_OFF;   // z2, later z4
    float* bufB = ws + BUFB_OFF;   // z3
    float* part = ws + PART_OFF;

    prep_kernel<<<8, 256, 0, stream>>>(c1w, c2w, c3w, c4w, mask, ws);
    k1_fused<<<dim3(6, 3, 256), 256, 0, stream>>>(x, wt1, wt2, c1b, c2b, bufA);
    conv8_kernel<<<dim3(3, 2, 256), 256, 0, stream>>>(bufA, bufB, wt3, c3b, 0); // conv3
    conv8_kernel<<<dim3(3, 2, 256), 256, 0, stream>>>(bufB, bufA, wt4, c4b, 1); // conv4+relu
    mlp_kernel<<<1152, 256, 0, stream>>>(bufA, W1, b1, W2, b2, W3, mv, part);
    reduce_kernel<<<1, 256, 0, stream>>>(part, ab, (float*)d_out);
}

// Round 4
// 373.646 us; speedup vs baseline: 3.7442x; 1.0192x over previous
//
#include <hip/hip_runtime.h>
#include <math.h>

// ws layout (float offsets). Total ~77 MB.
#define WT1_OFF 0
#define WT2_OFF 512
#define WT3_OFF 2560
#define WT4_OFF 4608
#define MV_OFF  6656
#define BUFA_OFF 16384
#define ZSZ (256*48*96*8)            // 9437184 floats
#define BUFB_OFF (BUFA_OFF + ZSZ)
#define PART_OFF (BUFA_OFF + 2*ZSZ)  // 1152*256 floats

// Bijective LDS swizzle: float index for (pixel, channel-half). XORs bank
// bits [4:2] with pixel bits [5:3]; float4 groups stay contiguous/aligned.
// Write and read MUST both use this map (rule #21).
__device__ __forceinline__ int swz8(int pix) {
    return (pix * 8) ^ (((pix >> 3) & 7) << 2);
}

// ---------------- K0: weight re-layout + mask precompute ----------------
__global__ void prep_kernel(const float* __restrict__ c1w, const float* __restrict__ c2w,
                            const float* __restrict__ c3w, const float* __restrict__ c4w,
                            const float* __restrict__ mask, float* __restrict__ ws) {
    int idx = blockIdx.x * blockDim.x + threadIdx.x;
    if (idx < 1600) {
        int co = idx & 7, rest = idx >> 3;
        int dx = rest % 5, dy = (rest / 5) % 5, ci = rest / 25;
        int src = ((co * 8 + ci) * 5 + dy) * 5 + dx;
        ws[WT2_OFF + idx] = c2w[src];
        ws[WT3_OFF + idx] = c3w[src];
        ws[WT4_OFF + idx] = c4w[src];
    }
    if (idx < 200) {
        int co = idx & 7, rest = idx >> 3;
        int dx = rest % 5, dy = rest / 5;
        ws[WT1_OFF + idx] = c1w[co * 25 + dy * 5 + dx];
    }
    if (idx < 1152) {
        int i = idx / 48, j = idx % 48;
        ws[MV_OFF + idx] = (mask[i * 8 * 384 + j * 8] > 0.5f) ? 1.0f : 0.0f;
    }
}

// ---------------- K1: ds + conv1 + conv2 + relu + maxpool ----------------
// Block tile: 16 conv2-rows x 64 conv2-cols -> pooled 8x32.
__global__ __launch_bounds__(256) void k1_fused(
        const float* __restrict__ x, const float* __restrict__ wt1,
        const float* __restrict__ wt2, const float* __restrict__ c1b,
        const float* __restrict__ c2b, float* __restrict__ z2) {
    __shared__ float xdbuf[24][72];                 // 6,912 B
    __shared__ __align__(16) float z1f[20 * 68 * 8]; // 43,520 B, swizzled NHWC
    const int rt = blockIdx.x;   // 0..5
    const int ct = blockIdx.y;   // 0..2
    const int b  = blockIdx.z;
    const int tid = threadIdx.x;
    const int ry0 = rt * 16, cx0 = ct * 64;

    // phase 0: 2x2 avg downsample into xdbuf
    for (int i = tid; i < 24 * 36; i += 256) {
        int pr = i / 36, pj = i % 36;
        int gy = ry0 - 4 + pr, gx = cx0 - 4 + 2 * pj;
        float v0 = 0.f, v1 = 0.f;
        if (gy >= 0 && gy < 96 && gx >= 0 && gx < 192) {
            const float* p = x + (size_t)b * (192 * 384) + (2 * gy) * 384 + 2 * gx;
            float4 a = *(const float4*)p;
            float4 c = *(const float4*)(p + 384);
            v0 = (a.x + a.y + c.x + c.y) * 0.25f;
            v1 = (a.z + a.w + c.z + c.w) * 0.25f;
        }
        xdbuf[pr][2 * pj]     = v0;
        xdbuf[pr][2 * pj + 1] = v1;
    }
    __syncthreads();

    // phase 1: conv1 (1->8, +bias) into swizzled z1f; out-of-image -> 0.
    for (int i = tid; i < 20 * 68; i += 256) {
        int iy = i / 68, ix = i % 68;
        int gy = ry0 - 2 + iy, gx = cx0 - 2 + ix;
        float acc[8];
        if (gy >= 0 && gy < 96 && gx >= 0 && gx < 192) {
#pragma unroll
            for (int co = 0; co < 8; ++co) acc[co] = c1b[co];
#pragma unroll
            for (int dy = 0; dy < 5; ++dy)
#pragma unroll
                for (int dx = 0; dx < 5; ++dx) {
                    float v = xdbuf[iy + dy][ix + dx];
#pragma unroll
                    for (int co = 0; co < 8; ++co)
                        acc[co] = fmaf(v, wt1[(dy * 5 + dx) * 8 + co], acc[co]);
                }
        } else {
#pragma unroll
            for (int co = 0; co < 8; ++co) acc[co] = 0.f;
        }
        int s = swz8(i);
        *(float4*)&z1f[s]     = make_float4(acc[0], acc[1], acc[2], acc[3]);
        *(float4*)&z1f[s ^ 4] = make_float4(acc[4], acc[5], acc[6], acc[7]);
    }
    __syncthreads();

    // phase 2: conv2 (8->8) over 4 consecutive cols per thread.
    const int rr = tid >> 4, cg = tid & 15;
    const int x0 = cg * 4;
    float acc[4][8];
#pragma unroll
    for (int p = 0; p < 4; ++p)
#pragma unroll
        for (int co = 0; co < 8; ++co) acc[p][co] = c2b[co];

#pragma unroll
    for (int dy = 0; dy < 5; ++dy) {
        const int rowbase = (rr + dy) * 68 + x0;
        float v[8][8];
#pragma unroll
        for (int c = 0; c < 8; ++c) {
            int s = swz8(rowbase + c);
            float4 p0 = *(const float4*)&z1f[s];
            float4 p1 = *(const float4*)&z1f[s ^ 4];
            v[c][0] = p0.x; v[c][1] = p0.y; v[c][2] = p0.z; v[c][3] = p0.w;
            v[c][4] = p1.x; v[c][5] = p1.y; v[c][6] = p1.z; v[c][7] = p1.w;
        }
#pragma unroll
        for (int dx = 0; dx < 5; ++dx)
#pragma unroll
            for (int ci = 0; ci < 8; ++ci) {
                const float* wp = wt2 + ((ci * 5 + dy) * 5 + dx) * 8;
#pragma unroll
                for (int p = 0; p < 4; ++p) {
                    float vv = v[p + dx][ci];
#pragma unroll
                    for (int co = 0; co < 8; ++co)
                        acc[p][co] = fmaf(vv, wp[co], acc[p][co]);
                }
            }
    }

    // relu + 2x2 maxpool: col-pairs in-thread, row pair via shfl_xor(16).
    float po[2][8];
#pragma unroll
    for (int q = 0; q < 2; ++q)
#pragma unroll
        for (int co = 0; co < 8; ++co)
            po[q][co] = fmaxf(fmaxf(acc[2 * q][co], acc[2 * q + 1][co]), 0.f);
#pragma unroll
    for (int q = 0; q < 2; ++q)
#pragma unroll
        for (int co = 0; co < 8; ++co) {
            float other = __shfl_xor(po[q][co], 16);
            po[q][co] = fmaxf(po[q][co], other);
        }
    if ((rr & 1) == 0) {
        int pyr = (ry0 + rr) >> 1;
        int pxc = (cx0 + x0) >> 1;
        float* dst = z2 + (((size_t)b * 48 + pyr) * 96 + pxc) * 8;
        *(float4*)(dst + 0)  = make_float4(po[0][0], po[0][1], po[0][2], po[0][3]);
        *(float4*)(dst + 4)  = make_float4(po[0][4], po[0][5], po[0][6], po[0][7]);
        *(float4*)(dst + 8)  = make_float4(po[1][0], po[1][1], po[1][2], po[1][3]);
        *(float4*)(dst + 12) = make_float4(po[1][4], po[1][5], po[1][6], po[1][7]);
    }
}

// ---------------- K2/K3: 8->8 conv, NHWC, SAME, optional relu -----------
// Tile: 16 rows x 48 cols (2 col tiles). LDS 33.3 KB -> 4 blocks/CU.
__global__ __launch_bounds__(256) void conv8_kernel(
        const float* __restrict__ in, float* __restrict__ out,
        const float* __restrict__ wt, const float* __restrict__ bias, int do_relu) {
    __shared__ __align__(16) float inbuf[20 * 52 * 8];  // 33,280 B, swizzled
    const int rt = blockIdx.x, ctile = blockIdx.y, b = blockIdx.z;
    const int ry0 = rt * 16, cx0 = ctile * 48;
    const int tid = threadIdx.x;

    // stage 20x52x8 region (zero-padded), swizzled writes
    for (int u = tid; u < 20 * 52 * 2; u += 256) {
        int half = u & 1, pix = u >> 1;
        int r = pix / 52, col = pix % 52;
        int gy = ry0 - 2 + r, gc = cx0 - 2 + col;
        float4 val = make_float4(0.f, 0.f, 0.f, 0.f);
        if (gy >= 0 && gy < 48 && gc >= 0 && gc < 96)
            val = *(const float4*)(in + (((size_t)b * 48 + gy) * 96 + gc) * 8 + half * 4);
        *(float4*)&inbuf[swz8(pix) ^ (half * 4)] = val;
    }
    __syncthreads();

    const int rr = tid >> 4, cg = tid & 15;
    const int x0 = cg * 3;
    float acc[3][8];
#pragma unroll
    for (int p = 0; p < 3; ++p)
#pragma unroll
        for (int co = 0; co < 8; ++co) acc[p][co] = bias[co];

#pragma unroll
    for (int dy = 0; dy < 5; ++dy) {
        const int rowbase = (rr + dy) * 52 + x0;
        float v[7][8];
#pragma unroll
        for (int c = 0; c < 7; ++c) {
            int s = swz8(rowbase + c);
            float4 p0 = *(const float4*)&inbuf[s];
            float4 p1 = *(const float4*)&inbuf[s ^ 4];
            v[c][0] = p0.x; v[c][1] = p0.y; v[c][2] = p0.z; v[c][3] = p0.w;
            v[c][4] = p1.x; v[c][5] = p1.y; v[c][6] = p1.z; v[c][7] = p1.w;
        }
#pragma unroll
        for (int dx = 0; dx < 5; ++dx)
#pragma unroll
            for (int ci = 0; ci < 8; ++ci) {
                const float* wp = wt + ((ci * 5 + dy) * 5 + dx) * 8;
#pragma unroll
                for (int p = 0; p < 3; ++p) {
                    float vv = v[p + dx][ci];
#pragma unroll
                    for (int co = 0; co < 8; ++co)
                        acc[p][co] = fmaf(vv, wp[co], acc[p][co]);
                }
            }
    }
#pragma unroll
    for (int p = 0; p < 3; ++p) {
        float o[8];
#pragma unroll
        for (int co = 0; co < 8; ++co)
            o[co] = do_relu ? fmaxf(acc[p][co], 0.f) : acc[p][co];
        float* dst = out + (((size_t)b * 48 + ry0 + rr) * 96 + (cx0 + x0 + p)) * 8;
        *(float4*)dst = make_float4(o[0], o[1], o[2], o[3]);
        *(float4*)(dst + 4) = make_float4(o[4], o[5], o[6], o[7]);
    }
}

// ---------------- K4: per-feature MLP (pool fused into load) ------------
__global__ __launch_bounds__(256) void mlp_kernel(
        const float* __restrict__ z4, const float* __restrict__ W1,
        const float* __restrict__ b1, const float* __restrict__ W2,
        const float* __restrict__ b2, const float* __restrict__ W3,
        const float* __restrict__ mv, float* __restrict__ part) {
    const int f = blockIdx.x;
    const int bb = threadIdx.x;
    if (mv[f] == 0.f) { part[(size_t)f * 256 + bb] = 0.f; return; }
    const int y = f / 48, xcol = f % 48;
    const float* src = z4 + (((size_t)bb * 48 + 2 * y) * 96 + 2 * xcol) * 8;
    float p00[8], p01[8], p10[8], p11[8];
    {
        float4 a0 = *(const float4*)(src);
        float4 a1 = *(const float4*)(src + 4);
        float4 a2 = *(const float4*)(src + 8);
        float4 a3 = *(const float4*)(src + 12);
        float4 c0 = *(const float4*)(src + 96 * 8);
        float4 c1 = *(const float4*)(src + 96 * 8 + 4);
        float4 c2 = *(const float4*)(src + 96 * 8 + 8);
        float4 c3 = *(const float4*)(src + 96 * 8 + 12);
        p00[0]=a0.x;p00[1]=a0.y;p00[2]=a0.z;p00[3]=a0.w;p00[4]=a1.x;p00[5]=a1.y;p00[6]=a1.z;p00[7]=a1.w;
        p01[0]=a2.x;p01[1]=a2.y;p01[2]=a2.z;p01[3]=a2.w;p01[4]=a3.x;p01[5]=a3.y;p01[6]=a3.z;p01[7]=a3.w;
        p10[0]=c0.x;p10[1]=c0.y;p10[2]=c0.z;p10[3]=c0.w;p10[4]=c1.x;p10[5]=c1.y;p10[6]=c1.z;p10[7]=c1.w;
        p11[0]=c2.x;p11[1]=c2.y;p11[2]=c2.z;p11[3]=c2.w;p11[4]=c3.x;p11[5]=c3.y;p11[6]=c3.z;p11[7]=c3.w;
    }
    float h[8];
#pragma unroll
    for (int c = 0; c < 8; ++c)
        h[c] = fmaxf(fmaxf(p00[c], p01[c]), fmaxf(p10[c], p11[c]));

    const float* w1p = W1 + (size_t)f * 8 * 32;
    const float* b1p = b1 + (size_t)f * 32;
    float t1[32];
#pragma unroll
    for (int j = 0; j < 32; ++j) t1[j] = b1p[j];
    for (int c = 0; c < 8; ++c) {
        float hv = h[c];
        const float* wp = w1p + c * 32;
#pragma unroll
        for (int j = 0; j < 32; ++j) t1[j] = fmaf(hv, wp[j], t1[j]);
    }
#pragma unroll
    for (int j = 0; j < 32; ++j) t1[j] = fmaxf(t1[j], 0.f);

    const float* w2p = W2 + (size_t)f * 32 * 32;
    const float* b2p = b2 + (size_t)f * 32;
    float t2[32];
#pragma unroll
    for (int g = 0; g < 32; ++g) t2[g] = b2p[g];
    for (int j = 0; j < 32; ++j) {
        float tv = t1[j];
        const float* wp = w2p + j * 32;
#pragma unroll
        for (int g = 0; g < 32; ++g) t2[g] = fmaf(tv, wp[g], t2[g]);
    }
    const float* w3p = W3 + (size_t)f * 32;
    float s = 0.f;
#pragma unroll
    for (int g = 0; g < 32; ++g) s = fmaf(fmaxf(t2[g], 0.f), w3p[g], s);
    part[(size_t)f * 256 + bb] = s;
}

// ---------------- K5: reduce over features + bias + sigmoid -------------
__global__ void reduce_kernel(const float* __restrict__ part, const float* __restrict__ ab,
                              float* __restrict__ out) {
    int bb = threadIdx.x;
    float s0 = 0.f, s1 = 0.f, s2 = 0.f, s3 = 0.f;
    for (int f = 0; f < 1152; f += 4) {
        s0 += part[(size_t)(f + 0) * 256 + bb];
        s1 += part[(size_t)(f + 1) * 256 + bb];
        s2 += part[(size_t)(f + 2) * 256 + bb];
        s3 += part[(size_t)(f + 3) * 256 + bb];
    }
    float s = (s0 + s1) + (s2 + s3) + ab[0];
    out[bb] = 1.f / (1.f + expf(-s));
}

extern "C" void kernel_launch(void* const* d_in, const int* in_sizes, int n_in,
                              void* d_out, int out_size, void* d_ws, size_t ws_size,
                              hipStream_t stream) {
    const float* x    = (const float*)d_in[0];
    const float* mask = (const float*)d_in[1];
    const float* c1w  = (const float*)d_in[2];
    const float* c1b  = (const float*)d_in[3];
    const float* c2w  = (const float*)d_in[4];
    const float* c2b  = (const float*)d_in[5];
    const float* c3w  = (const float*)d_in[6];
    const float* c3b  = (const float*)d_in[7];
    const float* c4w  = (const float*)d_in[8];
    const float* c4b  = (const float*)d_in[9];
    const float* W1   = (const float*)d_in[10];
    const float* b1   = (const float*)d_in[11];
    const float* W2   = (const float*)d_in[12];
    const float* b2   = (const float*)d_in[13];
    const float* W3   = (const float*)d_in[14];
    const float* ab   = (const float*)d_in[15];
    float* ws = (float*)d_ws;

    float* wt1  = ws + WT1_OFF;
    float* wt2  = ws + WT2_OFF;
    float* wt3  = ws + WT3_OFF;
    float* wt4  = ws + WT4_OFF;
    float* mv   = ws + MV_OFF;
    float* bufA = ws + BUFA_OFF;   // z2, later z4
    float* bufB = ws + BUFB_OFF;   // z3
    float* part = ws + PART_OFF;

    prep_kernel<<<8, 256, 0, stream>>>(c1w, c2w, c3w, c4w, mask, ws);
    k1_fused<<<dim3(6, 3, 256), 256, 0, stream>>>(x, wt1, wt2, c1b, c2b, bufA);
    conv8_kernel<<<dim3(3, 2, 256), 256, 0, stream>>>(bufA, bufB, wt3, c3b, 0); // conv3
    conv8_kernel<<<dim3(3, 2, 256), 256, 0, stream>>>(bufB, bufA, wt4, c4b, 1); // conv4+relu
    mlp_kernel<<<1152, 256, 0, stream>>>(bufA, W1, b1, W2, b2, W3, mv, part);
    reduce_kernel<<<1, 256, 0, stream>>>(part, ab, (float*)d_out);
}

// Round 6
// 256.211 us; speedup vs baseline: 5.4604x; 1.4584x over previous
//
#include <hip/hip_runtime.h>
#include <math.h>

typedef unsigned short ushort;
typedef unsigned int uint;
typedef __attribute__((ext_vector_type(8))) short bf16x8;
typedef __attribute__((ext_vector_type(8))) ushort ushort8;
typedef __attribute__((ext_vector_type(4))) float f32x4;

// ws layout (float offsets)
#define WT1_OFF   0          // 200 f   conv1 weights [tap][co]
#define MV_OFF    256        // 1152 f  mask vector
#define BIAS_OFF  1536       // 48 f    padded biases (conv2/3/4)
#define BFH_OFF   1600       // hi B-frags: 3*7*64*8 ushort = 5376 f
#define BFL_OFF   7040       // lo B-frags: same size
#define BUFA_OFF  16384      // activation buffer A: hi plane + lo plane
#define PLANE_U   9437184    // ushorts per plane (256*48*96*8)
#define BUFB_OFF  (BUFA_OFF + PLANE_U)        // (2 planes x 2B = PLANE_U floats)
#define PART_OFF  (BUFB_OFF + PLANE_U)        // 1152*256 f

__device__ __forceinline__ ushort f2bf(float f) {      // RTNE fp32->bf16
    union { float f; uint u; } a; a.f = f;
    uint u = a.u;
    return (ushort)((u + 0x7FFFu + ((u >> 16) & 1u)) >> 16);
}
__device__ __forceinline__ float bf2f(ushort s) {
    union { uint u; float f; } a; a.u = ((uint)s) << 16; return a.f;
}
// split v into hi+lo bf16
__device__ __forceinline__ void split_bf(float v, ushort& h, ushort& l) {
    h = f2bf(v);
    l = f2bf(v - bf2f(h));
}

// ---------------- K0: weights/mask/bias/B-frag precompute ----------------
__global__ void prep_kernel(const float* __restrict__ c1w, const float* __restrict__ c2w,
                            const float* __restrict__ c3w, const float* __restrict__ c4w,
                            const float* __restrict__ c2b, const float* __restrict__ c3b,
                            const float* __restrict__ c4b,
                            const float* __restrict__ mask, float* __restrict__ ws) {
    int idx = blockIdx.x * blockDim.x + threadIdx.x;
    if (idx < 200) {                       // conv1 weights -> [tap][co]
        int co = idx & 7, rest = idx >> 3;
        int dx = rest % 5, dy = rest / 5;
        ws[WT1_OFF + idx] = c1w[co * 25 + dy * 5 + dx];
    }
    if (idx < 1152) {
        int i = idx / 48, j = idx % 48;
        ws[MV_OFF + idx] = (mask[i * 8 * 384 + j * 8] > 0.5f) ? 1.0f : 0.0f;
    }
    if (idx < 48) {                        // padded biases
        int c = idx >> 4, co = idx & 15;
        const float* b = (c == 0) ? c2b : (c == 1) ? c3b : c4b;
        ws[BIAS_OFF + idx] = (co < 8) ? b[co] : 0.f;
    }
    if (idx < 1344) {                      // B-frags: lane l holds B[k=(l>>4)*8+j][col=l&15]
        int c = idx / 448, rem = idx % 448;
        int g = rem >> 6, l = rem & 63;
        int tg = l >> 4, co = l & 15;
        int tap = g * 4 + tg;
        const float* wsrc = (c == 0) ? c2w : (c == 1) ? c3w : c4w;
        ushort* bh = (ushort*)(ws + BFH_OFF) + (size_t)(c * 448 + g * 64 + l) * 8;
        ushort* bl = (ushort*)(ws + BFL_OFF) + (size_t)(c * 448 + g * 64 + l) * 8;
#pragma unroll
        for (int j = 0; j < 8; ++j) {      // j = ci
            float v = 0.f;
            if (tap < 25 && co < 8)
                v = wsrc[((co * 8 + j) * 5 + tap / 5) * 5 + (tap % 5)];
            ushort h, lo; split_bf(v, h, lo);
            bh[j] = h; bl[j] = lo;
        }
    }
}

// ---------------- K1: ds + conv1(VALU) + conv2(split-MFMA) + relu + pool --
// Tile: 16 conv2-rows x 64 cols -> pooled 8x32. 4 waves; wave w rows 4w..4w+3.
__global__ __launch_bounds__(256) void k1_fused(
        const float* __restrict__ x, const float* __restrict__ wt1,
        const float* __restrict__ c1b,
        const ushort* __restrict__ bfh, const ushort* __restrict__ bfl,
        const float* __restrict__ biaspad, ushort* __restrict__ z2) {
    __shared__ float xdbuf[24][72];           // 6,912 B
    __shared__ ushort z1h[20 * 68 * 8];       // 21,760 B
    __shared__ ushort z1l[20 * 68 * 8];       // 21,760 B
    __shared__ ushort z2bh[8 * 32 * 8];       // 4,096 B
    __shared__ ushort z2bl[8 * 32 * 8];       // 4,096 B
    const int rt = blockIdx.x, ct = blockIdx.y, b = blockIdx.z;
    const int tid = threadIdx.x;
    const int ry0 = rt * 16, cx0 = ct * 64;

    // phase 0: 2x2 avg downsample
    for (int i = tid; i < 24 * 36; i += 256) {
        int pr = i / 36, pj = i % 36;
        int gy = ry0 - 4 + pr, gx = cx0 - 4 + 2 * pj;
        float v0 = 0.f, v1 = 0.f;
        if (gy >= 0 && gy < 96 && gx >= 0 && gx < 192) {
            const float* p = x + (size_t)b * (192 * 384) + (2 * gy) * 384 + 2 * gx;
            float4 a = *(const float4*)p;
            float4 c = *(const float4*)(p + 384);
            v0 = (a.x + a.y + c.x + c.y) * 0.25f;
            v1 = (a.z + a.w + c.z + c.w) * 0.25f;
        }
        xdbuf[pr][2 * pj]     = v0;
        xdbuf[pr][2 * pj + 1] = v1;
    }
    __syncthreads();

    // phase 1: conv1 -> split bf16 z1 planes; OOB -> 0
    for (int i = tid; i < 20 * 68; i += 256) {
        int iy = i / 68, ix = i % 68;
        int gy = ry0 - 2 + iy, gx = cx0 - 2 + ix;
        float acc[8];
        if (gy >= 0 && gy < 96 && gx >= 0 && gx < 192) {
#pragma unroll
            for (int co = 0; co < 8; ++co) acc[co] = c1b[co];
#pragma unroll
            for (int dy = 0; dy < 5; ++dy)
#pragma unroll
                for (int dx = 0; dx < 5; ++dx) {
                    float v = xdbuf[iy + dy][ix + dx];
#pragma unroll
                    for (int co = 0; co < 8; ++co)
                        acc[co] = fmaf(v, wt1[(dy * 5 + dx) * 8 + co], acc[co]);
                }
        } else {
#pragma unroll
            for (int co = 0; co < 8; ++co) acc[co] = 0.f;
        }
        ushort8 uh, ul;
#pragma unroll
        for (int co = 0; co < 8; ++co) {
            ushort h, lo; split_bf(acc[co], h, lo);
            uh[co] = h; ul[co] = lo;
        }
        *(ushort8*)&z1h[i * 8] = uh;
        *(ushort8*)&z1l[i * 8] = ul;
    }
    __syncthreads();

    // phase 2: conv2 via split MFMA (K = 4 taps x 8 ci), + bias, relu, pool
    const int lane = tid & 63, w = tid >> 6;
    const int p = lane & 15, tg = lane >> 4;
    bf16x8 bwh[7], bwl[7];
#pragma unroll
    for (int g = 0; g < 7; ++g) {
        bwh[g] = *(const bf16x8*)(bfh + (size_t)(g * 64 + lane) * 8);
        bwl[g] = *(const bf16x8*)(bfl + (size_t)(g * 64 + lane) * 8);
    }
    const float bias = biaspad[lane & 15];
    int off[7];
#pragma unroll
    for (int g = 0; g < 7; ++g) {
        int t = g * 4 + tg; t = (t > 24) ? 24 : t;   // pad taps: zero weights
        off[g] = ((t / 5) * 68 + (t % 5)) * 8;
    }
    float stash[4][2];
#pragma unroll
    for (int rl = 0; rl < 4; ++rl) {
        const int r = 4 * w + rl;
#pragma unroll
        for (int cg = 0; cg < 4; ++cg) {
            f32x4 acc = {0.f, 0.f, 0.f, 0.f};
            const int base = (r * 68 + cg * 16 + p) * 8;
#pragma unroll
            for (int g = 0; g < 7; ++g) {
                bf16x8 ah = *(const bf16x8*)&z1h[base + off[g]];
                bf16x8 al = *(const bf16x8*)&z1l[base + off[g]];
                acc = __builtin_amdgcn_mfma_f32_16x16x32_bf16(ah, bwh[g], acc, 0, 0, 0);
                acc = __builtin_amdgcn_mfma_f32_16x16x32_bf16(ah, bwl[g], acc, 0, 0, 0);
                acc = __builtin_amdgcn_mfma_f32_16x16x32_bf16(al, bwh[g], acc, 0, 0, 0);
            }
            // C: col(lane&15)=co, row=tg*4+i=pixel. relu(max) + col-pair pool
            float p0 = fmaxf(fmaxf(acc[0], acc[1]) + bias, 0.f);
            float p1 = fmaxf(fmaxf(acc[2], acc[3]) + bias, 0.f);
            if ((rl & 1) == 0) {
                stash[cg][0] = p0; stash[cg][1] = p1;
            } else {
                p0 = fmaxf(p0, stash[cg][0]);
                p1 = fmaxf(p1, stash[cg][1]);
                if ((lane & 15) < 8) {
                    int pr = 2 * w + (rl >> 1);
                    int pc = cg * 8 + tg * 2;
                    ushort h0, l0, h1, l1;
                    split_bf(p0, h0, l0); split_bf(p1, h1, l1);
                    z2bh[(pr * 32 + pc) * 8 + (lane & 15)]     = h0;
                    z2bl[(pr * 32 + pc) * 8 + (lane & 15)]     = l0;
                    z2bh[(pr * 32 + pc + 1) * 8 + (lane & 15)] = h1;
                    z2bl[(pr * 32 + pc + 1) * 8 + (lane & 15)] = l1;
                }
            }
        }
    }
    __syncthreads();
    // cooperative pooled-tile store (8x32 px, 16B per plane)
    {
        int prr = tid >> 5, pcc = tid & 31;
        size_t gidx = ((size_t)(b * 48 + rt * 8 + prr) * 96 + ct * 32 + pcc) * 8;
        *(ushort8*)(z2 + gidx)           = *(const ushort8*)&z2bh[(prr * 32 + pcc) * 8];
        *(ushort8*)(z2 + PLANE_U + gidx) = *(const ushort8*)&z2bl[(prr * 32 + pcc) * 8];
    }
}

// ---------------- K2/K3: 8->8 conv via split MFMA, optional relu ---------
// Tile: 16 rows x 48 cols. 4 waves; wave w rows 4w..4w+3, 3 col-groups of 16.
__global__ __launch_bounds__(256) void conv_mfma(
        const ushort* __restrict__ in, ushort* __restrict__ out,
        const ushort* __restrict__ bfh, const ushort* __restrict__ bfl,
        const float* __restrict__ biaspad, int do_relu) {
    __shared__ ushort inh[20 * 52 * 8];       // 16,640 B
    __shared__ ushort inl[20 * 52 * 8];       // 16,640 B
    __shared__ ushort outh[16 * 48 * 8];      // 12,288 B
    __shared__ ushort outl[16 * 48 * 8];      // 12,288 B
    const int rt = blockIdx.x, ctile = blockIdx.y, b = blockIdx.z;
    const int ry0 = rt * 16, cx0 = ctile * 48;
    const int tid = threadIdx.x;

    // stage 20x52 px (16B per plane each), zero-padded
    for (int u = tid; u < 20 * 52; u += 256) {
        int r = u / 52, col = u % 52;
        int gy = ry0 - 2 + r, gc = cx0 - 2 + col;
        ushort8 vh = {0, 0, 0, 0, 0, 0, 0, 0};
        ushort8 vl = vh;
        if (gy >= 0 && gy < 48 && gc >= 0 && gc < 96) {
            size_t gidx = ((size_t)(b * 48 + gy) * 96 + gc) * 8;
            vh = *(const ushort8*)(in + gidx);
            vl = *(const ushort8*)(in + PLANE_U + gidx);
        }
        *(ushort8*)&inh[u * 8] = vh;
        *(ushort8*)&inl[u * 8] = vl;
    }
    __syncthreads();

    const int lane = tid & 63, w = tid >> 6;
    const int p = lane & 15, tg = lane >> 4;
    bf16x8 bwh[7], bwl[7];
#pragma unroll
    for (int g = 0; g < 7; ++g) {
        bwh[g] = *(const bf16x8*)(bfh + (size_t)(g * 64 + lane) * 8);
        bwl[g] = *(const bf16x8*)(bfl + (size_t)(g * 64 + lane) * 8);
    }
    const float bias = biaspad[lane & 15];
    int off[7];
#pragma unroll
    for (int g = 0; g < 7; ++g) {
        int t = g * 4 + tg; t = (t > 24) ? 24 : t;
        off[g] = ((t / 5) * 52 + (t % 5)) * 8;
    }
#pragma unroll
    for (int rl = 0; rl < 4; ++rl) {
        const int r = 4 * w + rl;
#pragma unroll
        for (int cg = 0; cg < 3; ++cg) {
            f32x4 acc = {0.f, 0.f, 0.f, 0.f};
            const int base = (r * 52 + cg * 16 + p) * 8;
#pragma unroll
            for (int g = 0; g < 7; ++g) {
                bf16x8 ah = *(const bf16x8*)&inh[base + off[g]];
                bf16x8 al = *(const bf16x8*)&inl[base + off[g]];
                acc = __builtin_amdgcn_mfma_f32_16x16x32_bf16(ah, bwh[g], acc, 0, 0, 0);
                acc = __builtin_amdgcn_mfma_f32_16x16x32_bf16(ah, bwl[g], acc, 0, 0, 0);
                acc = __builtin_amdgcn_mfma_f32_16x16x32_bf16(al, bwh[g], acc, 0, 0, 0);
            }
            if ((lane & 15) < 8) {
#pragma unroll
                for (int i = 0; i < 4; ++i) {
                    float v = acc[i] + bias;
                    if (do_relu) v = fmaxf(v, 0.f);
                    int px = r * 48 + cg * 16 + tg * 4 + i;
                    ushort h, lo; split_bf(v, h, lo);
                    outh[px * 8 + (lane & 15)] = h;
                    outl[px * 8 + (lane & 15)] = lo;
                }
            }
        }
    }
    __syncthreads();
    for (int u = tid; u < 16 * 48; u += 256) {
        int row = u / 48, col = u % 48;
        size_t gidx = ((size_t)(b * 48 + ry0 + row) * 96 + cx0 + col) * 8;
        *(ushort8*)(out + gidx)           = *(const ushort8*)&outh[u * 8];
        *(ushort8*)(out + PLANE_U + gidx) = *(const ushort8*)&outl[u * 8];
    }
}

// ---------------- K4: per-feature MLP (pool fused, split z4) -------------
__global__ __launch_bounds__(256) void mlp_kernel(
        const ushort* __restrict__ z4, const float* __restrict__ W1,
        const float* __restrict__ b1, const float* __restrict__ W2,
        const float* __restrict__ b2, const float* __restrict__ W3,
        const float* __restrict__ mv, float* __restrict__ part) {
    const int f = blockIdx.x;
    const int bb = threadIdx.x;
    if (mv[f] == 0.f) { part[(size_t)f * 256 + bb] = 0.f; return; }
    const int y = f / 48, xcol = f % 48;
    size_t s0i = (((size_t)bb * 48 + 2 * y) * 96 + 2 * xcol) * 8;
    ushort8 ah0 = *(const ushort8*)(z4 + s0i);
    ushort8 ah1 = *(const ushort8*)(z4 + s0i + 8);
    ushort8 ch0 = *(const ushort8*)(z4 + s0i + 96 * 8);
    ushort8 ch1 = *(const ushort8*)(z4 + s0i + 96 * 8 + 8);
    ushort8 al0 = *(const ushort8*)(z4 + PLANE_U + s0i);
    ushort8 al1 = *(const ushort8*)(z4 + PLANE_U + s0i + 8);
    ushort8 cl0 = *(const ushort8*)(z4 + PLANE_U + s0i + 96 * 8);
    ushort8 cl1 = *(const ushort8*)(z4 + PLANE_U + s0i + 96 * 8 + 8);
    float h[8];
#pragma unroll
    for (int c = 0; c < 8; ++c) {
        float v00 = bf2f(ah0[c]) + bf2f(al0[c]);
        float v01 = bf2f(ah1[c]) + bf2f(al1[c]);
        float v10 = bf2f(ch0[c]) + bf2f(cl0[c]);
        float v11 = bf2f(ch1[c]) + bf2f(cl1[c]);
        h[c] = fmaxf(fmaxf(v00, v01), fmaxf(v10, v11));
    }

    const float* w1p = W1 + (size_t)f * 8 * 32;
    const float* b1p = b1 + (size_t)f * 32;
    float t1[32];
#pragma unroll
    for (int j = 0; j < 32; ++j) t1[j] = b1p[j];
    for (int c = 0; c < 8; ++c) {
        float hv = h[c];
        const float* wp = w1p + c * 32;
#pragma unroll
        for (int j = 0; j < 32; ++j) t1[j] = fmaf(hv, wp[j], t1[j]);
    }
#pragma unroll
    for (int j = 0; j < 32; ++j) t1[j] = fmaxf(t1[j], 0.f);

    const float* w2p = W2 + (size_t)f * 32 * 32;
    const float* b2p = b2 + (size_t)f * 32;
    float t2[32];
#pragma unroll
    for (int g = 0; g < 32; ++g) t2[g] = b2p[g];
    for (int j = 0; j < 32; ++j) {
        float tv = t1[j];
        const float* wp = w2p + j * 32;
#pragma unroll
        for (int g = 0; g < 32; ++g) t2[g] = fmaf(tv, wp[g], t2[g]);
    }
    const float* w3p = W3 + (size_t)f * 32;
    float s = 0.f;
#pragma unroll
    for (int g = 0; g < 32; ++g) s = fmaf(fmaxf(t2[g], 0.f), w3p[g], s);
    part[(size_t)f * 256 + bb] = s;
}

// ---------------- K5: reduce over features + bias + sigmoid -------------
__global__ void reduce_kernel(const float* __restrict__ part, const float* __restrict__ ab,
                              float* __restrict__ out) {
    int bb = threadIdx.x;
    float s0 = 0.f, s1 = 0.f, s2 = 0.f, s3 = 0.f;
    for (int f = 0; f < 1152; f += 4) {
        s0 += part[(size_t)(f + 0) * 256 + bb];
        s1 += part[(size_t)(f + 1) * 256 + bb];
        s2 += part[(size_t)(f + 2) * 256 + bb];
        s3 += part[(size_t)(f + 3) * 256 + bb];
    }
    float s = (s0 + s1) + (s2 + s3) + ab[0];
    out[bb] = 1.f / (1.f + expf(-s));
}

extern "C" void kernel_launch(void* const* d_in, const int* in_sizes, int n_in,
                              void* d_out, int out_size, void* d_ws, size_t ws_size,
                              hipStream_t stream) {
    const float* x    = (const float*)d_in[0];
    const float* mask = (const float*)d_in[1];
    const float* c1w  = (const float*)d_in[2];
    const float* c1b  = (const float*)d_in[3];
    const float* c2w  = (const float*)d_in[4];
    const float* c2b  = (const float*)d_in[5];
    const float* c3w  = (const float*)d_in[6];
    const float* c3b  = (const float*)d_in[7];
    const float* c4w  = (const float*)d_in[8];
    const float* c4b  = (const float*)d_in[9];
    const float* W1   = (const float*)d_in[10];
    const float* b1   = (const float*)d_in[11];
    const float* W2   = (const float*)d_in[12];
    const float* b2   = (const float*)d_in[13];
    const float* W3   = (const float*)d_in[14];
    const float* ab   = (const float*)d_in[15];
    float* ws = (float*)d_ws;

    float*  wt1   = ws + WT1_OFF;
    float*  mv    = ws + MV_OFF;
    float*  biasp = ws + BIAS_OFF;
    ushort* bfh   = (ushort*)(ws + BFH_OFF);
    ushort* bfl   = (ushort*)(ws + BFL_OFF);
    ushort* bufA  = (ushort*)(ws + BUFA_OFF);  // z2, later z4
    ushort* bufB  = (ushort*)(ws + BUFB_OFF);  // z3
    float*  part  = ws + PART_OFF;

    prep_kernel<<<8, 256, 0, stream>>>(c1w, c2w, c3w, c4w, c2b, c3b, c4b, mask, ws);
    k1_fused<<<dim3(6, 3, 256), 256, 0, stream>>>(x, wt1, c1b, bfh, bfl, biasp, bufA);
    conv_mfma<<<dim3(3, 2, 256), 256, 0, stream>>>(bufA, bufB, bfh + 448 * 8,
                                                   bfl + 448 * 8, biasp + 16, 0);   // conv3
    conv_mfma<<<dim3(3, 2, 256), 256, 0, stream>>>(bufB, bufA, bfh + 2 * 448 * 8,
                                                   bfl + 2 * 448 * 8, biasp + 32, 1); // conv4+relu
    mlp_kernel<<<1152, 256, 0, stream>>>(bufA, W1, b1, W2, b2, W3, mv, part);
    reduce_kernel<<<1, 256, 0, stream>>>(part, ab, (float*)d_out);
}